// Round 12
// baseline (157.649 us; speedup 1.0000x reference)
//
#include <hip/hip_runtime.h>
#include <math.h>

typedef __attribute__((ext_vector_type(8)))  short short8;
typedef __attribute__((ext_vector_type(4)))  float f32x4;
typedef __attribute__((ext_vector_type(16))) float f32x16;
typedef __attribute__((ext_vector_type(4)))  uint  uint4v;

#define BB  4
#define C1  128
#define C2  256
#define HH  128
#define WW  128
#define NPT 9
#define HWN (HH*WW)

// ---- workspace byte offsets ----
#define XT_OFF    0ull                        // bf16 xT[b][h][w][c]   : 16,777,216 B
#define WB4_OFF   16777216ull                 // bf16 wB4[n][ob][kc][lane][8] : 589,824 B
#define WOF32_OFF (WB4_OFF + 589824ull)       // f32  wof32[c][q][81]  :     82,944 B
#define BN_OFF    (WOF32_OFF + 82944ull)      // f32  bnA/bnB[256]     :      2,048 B
#define OFFP_OFF  (BN_OFF + 2048ull)          // f32  offp[18][65536] SoA : 4,718,592 B
// total 22,170,624 <= proven 22,694,912

__device__ __forceinline__ ushort f2bf(float f) {
  uint u = __builtin_bit_cast(uint, f);
  u += 0x7FFFu + ((u >> 16) & 1u);            // RNE
  return (ushort)(u >> 16);
}
__device__ __forceinline__ float u2f(uint u) {
  return __builtin_bit_cast(float, u);
}

// ---------------- weight / BN prep ----------------
// wB4 element t: j=t&7, lane=(t>>3)&63, kc=(t>>9)&7, ob=(t>>12)&7, n=t>>15
//   A-frag (M=32 o, K=16): o = ob*32 + (lane&31), c = kc*16 + (lane>>5)*8 + j
__global__ __launch_bounds__(256) void prep(
    const float* __restrict__ w_main, const float* __restrict__ w_off,
    const float* __restrict__ g, const float* __restrict__ be,
    const float* __restrict__ mu, const float* __restrict__ var,
    ushort* ws_u, float* ws_f) {
  int t = blockIdx.x * 256 + threadIdx.x;
  if (t < C1 * NPT * C2) {
    int j = t & 7, lane = (t >> 3) & 63, kc = (t >> 9) & 7;
    int ob = (t >> 12) & 7, n = t >> 15;
    int o = ob * 32 + (lane & 31);
    int c = kc * 16 + (lane >> 5) * 8 + j;
    ws_u[WB4_OFF / 2 + t] = f2bf(w_main[(o * C1 + c) * NPT + n]);
  } else if (t < C1 * NPT * C2 + 128 * 2 * 81) {  // wof32[(c*2+q)*81 + tap*9 + i]
    int e = t - C1 * NPT * C2;
    int c2 = e / 81, r81 = e - c2 * 81;
    int q = c2 & 1, c = c2 >> 1;
    int tap = r81 / 9, i = r81 - tap * 9;
    int oc = q * 9 + i;
    ws_f[WOF32_OFF / 4 + e] = w_off[(oc * C1 + c) * 9 + tap];
  } else if (t < C1 * NPT * C2 + 128 * 2 * 81 + C2) {
    int o = t - (C1 * NPT * C2 + 128 * 2 * 81);
    float inv = g[o] * rsqrtf(var[o] + 1e-5f);
    ws_f[BN_OFF / 4 + o] = inv;
    ws_f[BN_OFF / 4 + 256 + o] = be[o] - mu[o] * inv;
  }
}

// ---------------- x -> xT[b][h][w][c] bf16 (c-contiguous) ----------------
__global__ __launch_bounds__(256) void transpose_x(
    const float* __restrict__ x, ushort* ws_u) {
  __shared__ __align__(16) ushort tile[32][68];
  int bid = blockIdx.x;
  int wt = bid & 1, h = (bid >> 1) & 127, cb = (bid >> 8) & 3, b = bid >> 10;
  int c0 = cb * 32, w0 = wt * 64;
  int tid = threadIdx.x;
  int wl = tid & 63, rr = tid >> 6;
#pragma unroll
  for (int it = 0; it < 8; ++it) {
    int ci = it * 4 + rr;
    tile[ci][wl] = f2bf(x[(((size_t)b * C1 + c0 + ci) * HWN) + h * WW + w0 + wl]);
  }
  __syncthreads();
  int wl2 = tid >> 2, cg = tid & 3;
  short8 pk;
#pragma unroll
  for (int k = 0; k < 8; ++k) pk[k] = (short)tile[cg * 8 + k][wl2];
  *(short8*)(ws_u + XT_OFF / 2 +
             (((size_t)(b * HH + h) * WW + w0 + wl2) * C1 + c0 + cg * 8)) = pk;
}

// ---- fp32 offset conv, channel-split x4, SoA partials in d_out scratch ----
__global__ __launch_bounds__(256) void off_conv_part(
    const float* __restrict__ x, const float* __restrict__ b_off,
    const float* __restrict__ ws_f, float* __restrict__ part) {
  int blk = blockIdx.x;
  int cg = blk & 3, bh = blk >> 2;          // cg: 32-channel group
  int h = bh & 127, b = bh >> 7;
  int tid = threadIdx.x;
  int w = tid & 127, q = tid >> 7;
  int qu = __builtin_amdgcn_readfirstlane(q);
  const float* wq = ws_f + WOF32_OFF / 4 + qu * 81;
  const float* xb = x + ((size_t)b * C1 + cg * 32) * HWN;

  float acc[9];
#pragma unroll
  for (int i = 0; i < 9; ++i) acc[i] = (cg == 0) ? b_off[qu * 9 + i] : 0.f;

  int hc0 = (h >= 1) ? h - 1 : 0, hc2 = (h < 127) ? h + 1 : 127;
  int wc0 = (w >= 1) ? w - 1 : 0, wc2 = (w < 127) ? w + 1 : 127;
  bool vh0 = (h >= 1), vh2 = (h < 127);
  bool vw0 = (w >= 1), vw2 = (w < 127);
  int o[9];
  o[0] = hc0 * 128 + wc0; o[1] = hc0 * 128 + w; o[2] = hc0 * 128 + wc2;
  o[3] = h   * 128 + wc0; o[4] = h   * 128 + w; o[5] = h   * 128 + wc2;
  o[6] = hc2 * 128 + wc0; o[7] = hc2 * 128 + w; o[8] = hc2 * 128 + wc2;
  bool vm[9];
  vm[0] = vh0 && vw0; vm[1] = vh0; vm[2] = vh0 && vw2;
  vm[3] = vw0;        vm[4] = true; vm[5] = vw2;
  vm[6] = vh2 && vw0; vm[7] = vh2; vm[8] = vh2 && vw2;

  for (int ci = 0; ci < 32; ++ci) {
    const float* xc = xb + (size_t)ci * HWN;
    float xv[9];
#pragma unroll
    for (int k = 0; k < 9; ++k) {
      float rr = xc[o[k]];
      xv[k] = vm[k] ? rr : 0.f;
    }
    const float* wp = wq + (cg * 32 + ci) * 162;   // wave-uniform -> scalar loads
#pragma unroll
    for (int tap = 0; tap < 9; ++tap)
#pragma unroll
      for (int i = 0; i < 9; ++i)
        acc[i] = fmaf(xv[tap], wp[tap * 9 + i], acc[i]);
  }
  int pos = (b * HH + h) * WW + w;
#pragma unroll
  for (int i = 0; i < 9; ++i)
    part[(size_t)(cg * 18 + qu * 9 + i) * 65536 + pos] = acc[i];
}

// ---- reduce 4 SoA partial planes -> offp[oc][pos] (fixed order, coalesced) ----
__global__ __launch_bounds__(256) void off_reduce_soa(
    const float* __restrict__ part, float* __restrict__ ws_f) {
  int e = blockIdx.x * 256 + threadIdx.x;   // over 18*65536
  int oc = e >> 16, pos = e & 65535;
  float s = part[(size_t)oc * 65536 + pos]
          + part[(size_t)(18 + oc) * 65536 + pos]
          + part[(size_t)(36 + oc) * 65536 + pos]
          + part[(size_t)(54 + oc) * 65536 + pos];
  ws_f[OFFP_OFF / 4 + (size_t)oc * 65536 + pos] = s;
}

// --- fused gather + 32x32x16 MFMA GEMM + BN + SiLU (16 waves, <=64 regs) ---
#define ALDS_STRIDE 136   // ushorts per 64-pos row (128 + 8 pad), 16B-aligned rows
__global__ __launch_bounds__(1024, 8) void akconv_main_mfma32(
    const ushort* ws_u, const float* ws_f, float* out) {
  __shared__ ushort sxy[576];                       // (x0<<8)|y0
  __shared__ __align__(16) f32x4 swgt[576];         // 4 bilinear weights, f32
  __shared__ __align__(16) ushort alds[2][64 * ALDS_STRIDE];

  int tid = threadIdx.x;
  int blk = blockIdx.x;
  // XCD-aware decode: each XCD (blk&7) owns one b-plane and one 64-row h-band
  int xcd = blk & 7, idx = blk >> 3;
  int b  = xcd >> 1;
  int h  = ((xcd & 1) << 6) + (idx >> 1);
  int wt = idx & 1;
  int w0 = wt * 64;
  const float* offp = ws_f + OFFP_OFF / 4;

  // phase A: bilinear sample (x0,y0) + 4 weights; coalesced SoA offset reads
  if (tid < 576) {
    int n = tid >> 6, wl = tid & 63;
    int pos = (b * HH + h) * WW + w0 + wl;
    float ox = offp[(size_t)n * 65536 + pos];
    float oy = offp[(size_t)(9 + n) * 65536 + pos];
    float px = ox + (float)(n / 3) + (float)h;
    float py = oy + (float)(n - (n / 3) * 3) + (float)(w0 + wl);
    px = fminf(fmaxf(px, 0.f), 127.f);
    py = fminf(fmaxf(py, 0.f), 127.f);
    float x0 = floorf(px), y0 = floorf(py);
    float x1 = fminf(x0 + 1.f, 127.f), y1 = fminf(y0 + 1.f, 127.f);
    f32x4 g;
    g[0] = (1.f + (x0 - px)) * (1.f + (y0 - py));
    g[1] = (1.f - (x1 - px)) * (1.f - (y1 - py));
    g[2] = (1.f + (x0 - px)) * (1.f - (y1 - py));
    g[3] = (1.f - (x1 - px)) * (1.f + (y0 - py));
    sxy[tid] = (ushort)(((int)x0 << 8) | (int)y0);
    swgt[tid] = g;
  }

  const char* xTb = (const char*)ws_u + (size_t)b * (HWN * 256);
  const ushort* wB4 = ws_u + WB4_OFF / 2;
  int lane = tid & 63;
  int wv = __builtin_amdgcn_readfirstlane(tid >> 6);   // wave 0..15
  int obu = wv & 7;                   // o-block (32-wide), wave-uniform
  int phu = wv >> 3;                  // pos-half (32-wide), wave-uniform
  int posl = lane & 31;               // pos within half
  int hi   = lane >> 5;               // k-half selector
  int brow = (phu * 32 + posl) * ALDS_STRIDE;   // B-frag row base (ushorts)

  // per-thread build slot: ONE (pos, 16B c-octet)
  int p   = tid >> 4;                 // 0..63
  int oct = tid & 15;
  int coff = oct * 16;
  int wr = p * ALDS_STRIDE + oct * 8;

  f32x16 acc = {};

  __syncthreads();   // sxy/swgt visible

  short8 gv[4];
  f32x4 gw;

#define GLOAD(nn)                                                       \
  {                                                                     \
    int e = (nn) * 64 + p;                                              \
    int exy = sxy[e];                                                   \
    gw = swgt[e];                                                       \
    int ax0 = exy >> 8, ay0 = exy & 255;                                \
    int ax1 = min(ax0 + 1, 127), ay1 = min(ay0 + 1, 127);               \
    gv[0] = *(const short8*)(xTb + (ax0 << 15) + (ay0 << 8) + coff);    \
    gv[1] = *(const short8*)(xTb + (ax1 << 15) + (ay1 << 8) + coff);    \
    gv[2] = *(const short8*)(xTb + (ax0 << 15) + (ay1 << 8) + coff);    \
    gv[3] = *(const short8*)(xTb + (ax1 << 15) + (ay0 << 8) + coff);    \
  }

#define GCOMBINE(bufb)                                                  \
  {                                                                     \
    uint4v g0 = __builtin_bit_cast(uint4v, gv[0]);                      \
    uint4v g1 = __builtin_bit_cast(uint4v, gv[1]);                      \
    uint4v g2 = __builtin_bit_cast(uint4v, gv[2]);                      \
    uint4v pkv;                                                         \
    uint4v g3 = __builtin_bit_cast(uint4v, gv[3]);                      \
    _Pragma("unroll")                                                   \
    for (int jj = 0; jj < 4; ++jj) {                                    \
      float flo = gw[0] * u2f(g0[jj] << 16) + gw[1] * u2f(g1[jj] << 16) \
                + gw[2] * u2f(g2[jj] << 16) + gw[3] * u2f(g3[jj] << 16);\
      float fhi = gw[0] * u2f(g0[jj] & 0xffff0000u)                     \
                + gw[1] * u2f(g1[jj] & 0xffff0000u)                     \
                + gw[2] * u2f(g2[jj] & 0xffff0000u)                     \
                + gw[3] * u2f(g3[jj] & 0xffff0000u);                    \
      uint upk;                                                         \
      asm("v_cvt_pk_bf16_f32 %0, %1, %2" : "=v"(upk) : "v"(flo), "v"(fhi)); \
      pkv[jj] = upk;                                                    \
    }                                                                   \
    *(uint4v*)(&alds[bufb][wr]) = pkv;                                  \
  }

  // prologue: build n=0 into buf 0
  GLOAD(0);
  GCOMBINE(0);
  __syncthreads();

  for (int n = 0; n < 9; ++n) {
    int buf = n & 1;
    if (n < 8) GLOAD(n + 1);          // latency hides under MFMA via 8 waves/SIMD
#pragma unroll
    for (int kc = 0; kc < 8; ++kc) {
      short8 afrag = *(const short8*)(wB4 +
          (((size_t)(n * 8 + obu) * 8 + kc) * 64 + lane) * 8);   // contiguous 1KB/wave
      short8 bfrag = *(const short8*)(&alds[buf][brow + kc * 16 + hi * 8]);
      acc = __builtin_amdgcn_mfma_f32_32x32x16_bf16(afrag, bfrag, acc, 0, 0, 0);
    }
    if (n < 8) GCOMBINE(buf ^ 1);
    __syncthreads();
  }
#undef GLOAD
#undef GCOMBINE

  // epilogue: BN + SiLU; D col=lane&31 (pos), row=(reg&3)+8*(reg>>2)+4*hi (o)
  const float* bnA = ws_f + BN_OFF / 4;
  const float* bnB = bnA + 256;
  int posg = phu * 32 + posl;
#pragma unroll
  for (int q = 0; q < 4; ++q) {
#pragma unroll
    for (int jj = 0; jj < 4; ++jj) {
      int o = obu * 32 + jj + 8 * q + 4 * hi;
      float v = acc[q * 4 + jj] * bnA[o] + bnB[o];
      float sv = v / (1.f + __expf(-v));
      out[(((size_t)b * C2 + o) * HWN) + h * WW + w0 + posg] = sv;
    }
  }
}

extern "C" void kernel_launch(void* const* d_in, const int* in_sizes, int n_in,
                              void* d_out, int out_size, void* d_ws, size_t ws_size,
                              hipStream_t stream) {
  const float* x        = (const float*)d_in[0];
  const float* w_off    = (const float*)d_in[1];
  const float* b_off    = (const float*)d_in[2];
  const float* w_main   = (const float*)d_in[3];
  const float* bn_gamma = (const float*)d_in[4];
  const float* bn_beta  = (const float*)d_in[5];
  const float* bn_mean  = (const float*)d_in[6];
  const float* bn_var   = (const float*)d_in[7];
  ushort* ws_u = (ushort*)d_ws;
  float*  ws_f = (float*)d_ws;
  float*  out  = (float*)d_out;

  int prep_tasks = C1 * NPT * C2 + 128 * 2 * 81 + C2;   // 315904
  prep<<<(prep_tasks + 255) / 256, 256, 0, stream>>>(
      w_main, w_off, bn_gamma, bn_beta, bn_mean, bn_var, ws_u, ws_f);
  transpose_x<<<BB * 4 * HH * 2, 256, 0, stream>>>(x, ws_u);
  // offset conv: SoA partials into d_out scratch (later fully overwritten by main)
  off_conv_part<<<4 * BB * HH, 256, 0, stream>>>(x, b_off, ws_f, out);
  off_reduce_soa<<<(18 * 65536) / 256, 256, 0, stream>>>(out, ws_f);
  akconv_main_mfma32<<<BB * HH * 2, 1024, 0, stream>>>(ws_u, ws_f, out);
}

// Round 14
// 145.757 us; speedup vs baseline: 1.0816x; 1.0816x over previous
//
#include <hip/hip_runtime.h>
#include <math.h>

typedef __attribute__((ext_vector_type(8))) short short8;
typedef __attribute__((ext_vector_type(4))) float f32x4;
typedef __attribute__((ext_vector_type(4))) uint  uint4v;
typedef __attribute__((ext_vector_type(4))) int   int4v;

#define BB  4
#define C1  128
#define C2  256
#define HH  128
#define WW  128
#define NPT 9
#define HWN (HH*WW)

// ---- workspace byte offsets ----
#define XT_OFF    0ull                        // bf16 xT[b][h][w][c]   : 16,777,216 B
#define WB3_OFF   16777216ull                 // bf16 wB3[n][ob][kc][lane][8] : 589,824 B
#define WOF32_OFF (WB3_OFF + 589824ull)       // f32  wof32[c][q][81]  :     82,944 B
#define BN_OFF    (WOF32_OFF + 82944ull)      // f32  bnA/bnB[256]     :      2,048 B
#define OFFP_OFF  (BN_OFF + 2048ull)          // f32  offp[18][65536] SoA : 4,718,592 B
#define PART_OFF  (OFFP_OFF + 4718592ull)     // f32  part[72][65536] (fused mode) : 18,874,368 B
#define WS_BASE_NEED  (PART_OFF)              // 22,170,624 (proven available)
#define WS_FUSED_NEED (PART_OFF + 18874368ull) // 41,044,992 (gated)

__device__ __forceinline__ ushort f2bf(float f) {
  uint u = __builtin_bit_cast(uint, f);
  u += 0x7FFFu + ((u >> 16) & 1u);            // RNE
  return (ushort)(u >> 16);
}
__device__ __forceinline__ float u2f(uint u) {
  return __builtin_bit_cast(float, u);
}

// ---------------- weight / BN prep ----------------
// wB3 element t: j=t&7, lane=(t>>3)&63, kc=(t>>9)&3, ob=(t>>11)&15, n=t>>15
//   -> o = ob*16 + (lane&15), c = kc*32 + (lane>>4)*8 + j   (16x16x32 B-frag order)
__global__ __launch_bounds__(256) void prep(
    const float* __restrict__ w_main, const float* __restrict__ w_off,
    const float* __restrict__ g, const float* __restrict__ be,
    const float* __restrict__ mu, const float* __restrict__ var,
    ushort* ws_u, float* ws_f) {
  int t = blockIdx.x * 256 + threadIdx.x;
  if (t < C1 * NPT * C2) {
    int j = t & 7, lane = (t >> 3) & 63, kc = (t >> 9) & 3;
    int ob = (t >> 11) & 15, n = t >> 15;
    int o = ob * 16 + (lane & 15);
    int c = kc * 32 + (lane >> 4) * 8 + j;
    ws_u[WB3_OFF / 2 + t] = f2bf(w_main[(o * C1 + c) * NPT + n]);
  } else if (t < C1 * NPT * C2 + 128 * 2 * 81) {  // wof32[(c*2+q)*81 + tap*9 + i]
    int e = t - C1 * NPT * C2;
    int c2 = e / 81, r81 = e - c2 * 81;
    int q = c2 & 1, c = c2 >> 1;
    int tap = r81 / 9, i = r81 - tap * 9;
    int oc = q * 9 + i;
    ws_f[WOF32_OFF / 4 + e] = w_off[(oc * C1 + c) * 9 + tap];
  } else if (t < C1 * NPT * C2 + 128 * 2 * 81 + C2) {
    int o = t - (C1 * NPT * C2 + 128 * 2 * 81);
    float inv = g[o] * rsqrtf(var[o] + 1e-5f);
    ws_f[BN_OFF / 4 + o] = inv;
    ws_f[BN_OFF / 4 + 256 + o] = be[o] - mu[o] * inv;
  }
}

// ---------------- x -> xT[b][h][w][c] bf16 (c-contiguous) ----------------
__global__ __launch_bounds__(256) void transpose_x(
    const float* __restrict__ x, ushort* ws_u) {
  __shared__ __align__(16) ushort tile[32][68];
  int bid = blockIdx.x;
  int wt = bid & 1, h = (bid >> 1) & 127, cb = (bid >> 8) & 3, b = bid >> 10;
  int c0 = cb * 32, w0 = wt * 64;
  int tid = threadIdx.x;
  int wl = tid & 63, rr = tid >> 6;
#pragma unroll
  for (int it = 0; it < 8; ++it) {
    int ci = it * 4 + rr;
    tile[ci][wl] = f2bf(x[(((size_t)b * C1 + c0 + ci) * HWN) + h * WW + w0 + wl]);
  }
  __syncthreads();
  int wl2 = tid >> 2, cg = tid & 3;
  short8 pk;
#pragma unroll
  for (int k = 0; k < 8; ++k) pk[k] = (short)tile[cg * 8 + k][wl2];
  *(short8*)(ws_u + XT_OFF / 2 +
             (((size_t)(b * HH + h) * WW + w0 + wl2) * C1 + c0 + cg * 8)) = pk;
}

// ---- fp32 offset conv, channel-split x4, SoA partials (dst chosen host-side) ----
__global__ __launch_bounds__(256) void off_conv_part(
    const float* __restrict__ x, const float* __restrict__ b_off,
    const float* __restrict__ ws_f, float* __restrict__ part) {
  int blk = blockIdx.x;
  int cg = blk & 3, bh = blk >> 2;          // cg: 32-channel group
  int h = bh & 127, b = bh >> 7;
  int tid = threadIdx.x;
  int w = tid & 127, q = tid >> 7;
  int qu = __builtin_amdgcn_readfirstlane(q);
  const float* wq = ws_f + WOF32_OFF / 4 + qu * 81;
  const float* xb = x + ((size_t)b * C1 + cg * 32) * HWN;

  float acc[9];
#pragma unroll
  for (int i = 0; i < 9; ++i) acc[i] = (cg == 0) ? b_off[qu * 9 + i] : 0.f;

  int hc0 = (h >= 1) ? h - 1 : 0, hc2 = (h < 127) ? h + 1 : 127;
  int wc0 = (w >= 1) ? w - 1 : 0, wc2 = (w < 127) ? w + 1 : 127;
  bool vh0 = (h >= 1), vh2 = (h < 127);
  bool vw0 = (w >= 1), vw2 = (w < 127);
  int o[9];
  o[0] = hc0 * 128 + wc0; o[1] = hc0 * 128 + w; o[2] = hc0 * 128 + wc2;
  o[3] = h   * 128 + wc0; o[4] = h   * 128 + w; o[5] = h   * 128 + wc2;
  o[6] = hc2 * 128 + wc0; o[7] = hc2 * 128 + w; o[8] = hc2 * 128 + wc2;
  bool vm[9];
  vm[0] = vh0 && vw0; vm[1] = vh0; vm[2] = vh0 && vw2;
  vm[3] = vw0;        vm[4] = true; vm[5] = vw2;
  vm[6] = vh2 && vw0; vm[7] = vh2; vm[8] = vh2 && vw2;

  for (int ci = 0; ci < 32; ++ci) {
    const float* xc = xb + (size_t)ci * HWN;
    float xv[9];
#pragma unroll
    for (int k = 0; k < 9; ++k) {
      float rr = xc[o[k]];
      xv[k] = vm[k] ? rr : 0.f;
    }
    const float* wp = wq + (cg * 32 + ci) * 162;   // wave-uniform -> scalar loads
#pragma unroll
    for (int tap = 0; tap < 9; ++tap)
#pragma unroll
      for (int i = 0; i < 9; ++i)
        acc[i] = fmaf(xv[tap], wp[tap * 9 + i], acc[i]);
  }
  int pos = (b * HH + h) * WW + w;
#pragma unroll
  for (int i = 0; i < 9; ++i)
    part[(size_t)(cg * 18 + qu * 9 + i) * 65536 + pos] = acc[i];
}

// ---- reduce 4 SoA partial planes -> offp[oc][pos] (fallback mode only) ----
__global__ __launch_bounds__(256) void off_reduce_soa(
    const float* __restrict__ part, float* __restrict__ ws_f) {
  int e = blockIdx.x * 256 + threadIdx.x;   // over 18*65536
  int oc = e >> 16, pos = e & 65535;
  float s = part[(size_t)oc * 65536 + pos]
          + part[(size_t)(18 + oc) * 65536 + pos]
          + part[(size_t)(36 + oc) * 65536 + pos]
          + part[(size_t)(54 + oc) * 65536 + pos];
  ws_f[OFFP_OFF / 4 + (size_t)oc * 65536 + pos] = s;
}

// ------- fused gather + 16x16x32 MFMA GEMM + BN + SiLU (16 waves) -------
#define ALDS_STRIDE 136   // ushorts per 64-pos row (128 + 8 pad), 16B-aligned rows
__global__ __launch_bounds__(1024, 8) void akconv_main_mfma16(
    const ushort* ws_u, const float* ws_f, float* out, int fused) {
  __shared__ __align__(16) int4v sidx[576];          // 4 byte-offsets into xT b-plane
  __shared__ __align__(16) f32x4 swgt[576];          // 4 bilinear weights, f32
  __shared__ __align__(16) ushort alds[2][64 * ALDS_STRIDE];

  int tid = threadIdx.x;
  int blk = blockIdx.x;
  // XCD-aware decode: each XCD (blk&7) owns one b-plane and one 64-row h-band
  int xcd = blk & 7, idx = blk >> 3;
  int b  = xcd >> 1;
  int h  = ((xcd & 1) << 6) + (idx >> 1);
  int wt = idx & 1;
  int w0 = wt * 64;

  // phase A: bilinear offsets + weights; offsets either pre-reduced or 4-plane sum
  if (tid < 576) {
    int n = tid >> 6, wl = tid & 63;
    int pos = (b * HH + h) * WW + w0 + wl;
    float ox, oy;
    if (fused) {
      const float* pp = ws_f + PART_OFF / 4;
      ox = pp[(size_t)n * 65536 + pos]
         + pp[(size_t)(18 + n) * 65536 + pos]
         + pp[(size_t)(36 + n) * 65536 + pos]
         + pp[(size_t)(54 + n) * 65536 + pos];
      oy = pp[(size_t)(9 + n) * 65536 + pos]
         + pp[(size_t)(27 + n) * 65536 + pos]
         + pp[(size_t)(45 + n) * 65536 + pos]
         + pp[(size_t)(63 + n) * 65536 + pos];
    } else {
      const float* offp = ws_f + OFFP_OFF / 4;
      ox = offp[(size_t)n * 65536 + pos];
      oy = offp[(size_t)(9 + n) * 65536 + pos];
    }
    float px = ox + (float)(n / 3) + (float)h;
    float py = oy + (float)(n - (n / 3) * 3) + (float)(w0 + wl);
    px = fminf(fmaxf(px, 0.f), 127.f);
    py = fminf(fmaxf(py, 0.f), 127.f);
    float x0 = floorf(px), y0 = floorf(py);
    float x1 = fminf(x0 + 1.f, 127.f), y1 = fminf(y0 + 1.f, 127.f);
    f32x4 g;
    g[0] = (1.f + (x0 - px)) * (1.f + (y0 - py));
    g[1] = (1.f - (x1 - px)) * (1.f - (y1 - py));
    g[2] = (1.f + (x0 - px)) * (1.f - (y1 - py));
    g[3] = (1.f - (x1 - px)) * (1.f + (y0 - py));
    int ix0 = (int)x0, iy0 = (int)y0, ix1 = (int)x1, iy1 = (int)y1;
    int4v iv;
    iv[0] = (ix0 * WW + iy0) << 8;    // *256 B per (h,w) c-row
    iv[1] = (ix1 * WW + iy1) << 8;
    iv[2] = (ix0 * WW + iy1) << 8;
    iv[3] = (ix1 * WW + iy0) << 8;
    sidx[tid] = iv;
    swgt[tid] = g;
  }

  const char* xTb = (const char*)ws_u + (size_t)b * (HWN * 256);
  const ushort* wB3 = ws_u + WB3_OFF / 2;
  int lane = tid & 63, r = lane & 15, kg = lane >> 4;
  int wv = __builtin_amdgcn_readfirstlane(tid >> 6);   // wave = o-block 0..15

  // per-thread build slot: ONE (pos, 16B c-octet)
  int p   = tid >> 4;                 // 0..63
  int oct = tid & 15;
  int coff = oct * 16;
  int wr = p * ALDS_STRIDE + oct * 8;

  f32x4 acc[4];
#pragma unroll
  for (int mi = 0; mi < 4; ++mi) acc[mi] = (f32x4)0.0f;

  __syncthreads();   // sidx/swgt visible

  uint4v gv[4];
  f32x4 gw;

#define GLOAD(nn)                                                       \
  {                                                                     \
    int e = (nn) * 64 + p;                                              \
    int4v iv = sidx[e];                                                 \
    gw = swgt[e];                                                       \
    gv[0] = *(const uint4v*)(xTb + iv[0] + coff);                       \
    gv[1] = *(const uint4v*)(xTb + iv[1] + coff);                       \
    gv[2] = *(const uint4v*)(xTb + iv[2] + coff);                       \
    gv[3] = *(const uint4v*)(xTb + iv[3] + coff);                       \
  }

#define GCOMBINE(bufb)                                                  \
  {                                                                     \
    uint4v pkv;                                                         \
    _Pragma("unroll")                                                   \
    for (int jj = 0; jj < 4; ++jj) {                                    \
      float flo = gw[0] * u2f(gv[0][jj] << 16) + gw[1] * u2f(gv[1][jj] << 16) \
                + gw[2] * u2f(gv[2][jj] << 16) + gw[3] * u2f(gv[3][jj] << 16);\
      float fhi = gw[0] * u2f(gv[0][jj] & 0xffff0000u)                  \
                + gw[1] * u2f(gv[1][jj] & 0xffff0000u)                  \
                + gw[2] * u2f(gv[2][jj] & 0xffff0000u)                  \
                + gw[3] * u2f(gv[3][jj] & 0xffff0000u);                 \
      uint upk;                                                         \
      asm("v_cvt_pk_bf16_f32 %0, %1, %2" : "=v"(upk) : "v"(flo), "v"(fhi)); \
      pkv[jj] = upk;                                                    \
    }                                                                   \
    *(uint4v*)(&alds[bufb][wr]) = pkv;                                  \
  }

  // prologue: build n=0 into buf 0
  GLOAD(0);
  GCOMBINE(0);
  __syncthreads();

  for (int n = 0; n < 9; ++n) {
    int buf = n & 1;
    if (n < 8) GLOAD(n + 1);          // latency hides under MFMA via TLP
#pragma unroll
    for (int kc = 0; kc < 4; ++kc) {
      short8 bfrag = *(const short8*)(wB3 +
          (((size_t)(n * 16 + wv) * 4 + kc) * 64 + lane) * 8);   // contiguous 1KB/wave
#pragma unroll
      for (int mi = 0; mi < 4; ++mi) {
        short8 a = *(const short8*)(&alds[buf][(mi * 16 + r) * ALDS_STRIDE + (kc * 4 + kg) * 8]);
        acc[mi] = __builtin_amdgcn_mfma_f32_16x16x32_bf16(bfrag, a, acc[mi], 0, 0, 0);
      }
    }
    if (n < 8) GCOMBINE(buf ^ 1);
    __syncthreads();
  }
#undef GLOAD
#undef GCOMBINE

  // epilogue: BN + SiLU; D[row=o_sub][col=pos], stores coalesced along w
  const float* bnA = ws_f + BN_OFF / 4;
  const float* bnB = bnA + 256;
  int ob = wv * 16 + kg * 4;
#pragma unroll
  for (int j = 0; j < 4; ++j) {
    int o = ob + j;
    float sA = bnA[o], sB = bnB[o];
#pragma unroll
    for (int mi = 0; mi < 4; ++mi) {
      float v = acc[mi][j] * sA + sB;
      float sv = v / (1.f + __expf(-v));
      out[(((size_t)b * C2 + o) * HWN) + h * WW + w0 + mi * 16 + r] = sv;
    }
  }
}

extern "C" void kernel_launch(void* const* d_in, const int* in_sizes, int n_in,
                              void* d_out, int out_size, void* d_ws, size_t ws_size,
                              hipStream_t stream) {
  const float* x        = (const float*)d_in[0];
  const float* w_off    = (const float*)d_in[1];
  const float* b_off    = (const float*)d_in[2];
  const float* w_main   = (const float*)d_in[3];
  const float* bn_gamma = (const float*)d_in[4];
  const float* bn_beta  = (const float*)d_in[5];
  const float* bn_mean  = (const float*)d_in[6];
  const float* bn_var   = (const float*)d_in[7];
  ushort* ws_u = (ushort*)d_ws;
  float*  ws_f = (float*)d_ws;
  float*  out  = (float*)d_out;

  int fused = (ws_size >= WS_FUSED_NEED) ? 1 : 0;

  int prep_tasks = C1 * NPT * C2 + 128 * 2 * 81 + C2;   // 315904
  prep<<<(prep_tasks + 255) / 256, 256, 0, stream>>>(
      w_main, w_off, bn_gamma, bn_beta, bn_mean, bn_var, ws_u, ws_f);
  transpose_x<<<BB * 4 * HH * 2, 256, 0, stream>>>(x, ws_u);
  if (fused) {
    // partials live in ws; main kernel sums the 4 planes in phase A
    off_conv_part<<<4 * BB * HH, 256, 0, stream>>>(x, b_off, ws_f, ws_f + PART_OFF / 4);
  } else {
    // partials in d_out scratch (fully overwritten by main later)
    off_conv_part<<<4 * BB * HH, 256, 0, stream>>>(x, b_off, ws_f, out);
    off_reduce_soa<<<(18 * 65536) / 256, 256, 0, stream>>>(out, ws_f);
  }
  akconv_main_mfma16<<<BB * HH * 2, 1024, 0, stream>>>(ws_u, ws_f, out, fused);
}

// Round 15
// 138.247 us; speedup vs baseline: 1.1403x; 1.0543x over previous
//
#include <hip/hip_runtime.h>
#include <math.h>

typedef __attribute__((ext_vector_type(8))) short short8;
typedef __attribute__((ext_vector_type(4))) float f32x4;
typedef __attribute__((ext_vector_type(4))) uint  uint4v;
typedef __attribute__((ext_vector_type(4))) int   int4v;

#define BB  4
#define C1  128
#define C2  256
#define HH  128
#define WW  128
#define NPT 9
#define HWN (HH*WW)

// ---- workspace byte offsets ----
#define XT_OFF    0ull                        // bf16 xT[b][h][w][c]   : 16,777,216 B
#define WB3_OFF   16777216ull                 // bf16 wB3[n][ob][kc][lane][8] : 589,824 B
#define WOF32_OFF (WB3_OFF + 589824ull)       // f32  wof32[c][q][81]  :     82,944 B
#define BN_OFF    (WOF32_OFF + 82944ull)      // f32  bnA/bnB[256]     :      2,048 B
#define OFFP_OFF  (BN_OFF + 2048ull)          // f32  offp[18][65536] SoA : 4,718,592 B
#define PART_OFF  (OFFP_OFF + 4718592ull)     // f32  part[72][65536] (fused mode) : 18,874,368 B
#define WS_FUSED_NEED (PART_OFF + 18874368ull) // 41,044,992 (proven available in R14)

__device__ __forceinline__ ushort f2bf(float f) {
  uint u = __builtin_bit_cast(uint, f);
  u += 0x7FFFu + ((u >> 16) & 1u);            // RNE
  return (ushort)(u >> 16);
}
__device__ __forceinline__ float u2f(uint u) {
  return __builtin_bit_cast(float, u);
}

// ---------------- weight / BN prep (must precede stage1: off_conv reads wof32) ----------------
// wB3 element t: j=t&7, lane=(t>>3)&63, kc=(t>>9)&3, ob=(t>>11)&15, n=t>>15
//   -> o = ob*16 + (lane&15), c = kc*32 + (lane>>4)*8 + j   (16x16x32 B-frag order)
__global__ __launch_bounds__(256) void prep(
    const float* __restrict__ w_main, const float* __restrict__ w_off,
    const float* __restrict__ g, const float* __restrict__ be,
    const float* __restrict__ mu, const float* __restrict__ var,
    ushort* ws_u, float* ws_f) {
  int t = blockIdx.x * 256 + threadIdx.x;
  if (t < C1 * NPT * C2) {
    int j = t & 7, lane = (t >> 3) & 63, kc = (t >> 9) & 3;
    int ob = (t >> 11) & 15, n = t >> 15;
    int o = ob * 16 + (lane & 15);
    int c = kc * 32 + (lane >> 4) * 8 + j;
    ws_u[WB3_OFF / 2 + t] = f2bf(w_main[(o * C1 + c) * NPT + n]);
  } else if (t < C1 * NPT * C2 + 128 * 2 * 81) {  // wof32[(c*2+q)*81 + tap*9 + i]
    int e = t - C1 * NPT * C2;
    int c2 = e / 81, r81 = e - c2 * 81;
    int q = c2 & 1, c = c2 >> 1;
    int tap = r81 / 9, i = r81 - tap * 9;
    int oc = q * 9 + i;
    ws_f[WOF32_OFF / 4 + e] = w_off[(oc * C1 + c) * 9 + tap];
  } else if (t < C1 * NPT * C2 + 128 * 2 * 81 + C2) {
    int o = t - (C1 * NPT * C2 + 128 * 2 * 81);
    float inv = g[o] * rsqrtf(var[o] + 1e-5f);
    ws_f[BN_OFF / 4 + o] = inv;
    ws_f[BN_OFF / 4 + 256 + o] = be[o] - mu[o] * inv;
  }
}

// ---------------- stage1: fused off_conv (blocks 0..2047) + transpose_x (2048..6143) ----------------
// The two sub-kernels are independent; fusing overlaps the VALU-bound conv with the
// BW-bound transpose across CUs instead of serializing two dispatches.
__global__ __launch_bounds__(256) void stage1(
    const float* __restrict__ x, const float* __restrict__ b_off,
    const float* __restrict__ ws_f_ro, ushort* ws_u, float* __restrict__ part) {
  __shared__ __align__(16) ushort tile[32][68];
  int blk = blockIdx.x;
  int tid = threadIdx.x;

  if (blk < 4 * BB * HH) {
    // ---- off_conv_part body (verbatim R14) ----
    int cg = blk & 3, bh = blk >> 2;          // cg: 32-channel group
    int h = bh & 127, b = bh >> 7;
    int w = tid & 127, q = tid >> 7;
    int qu = __builtin_amdgcn_readfirstlane(q);
    const float* wq = ws_f_ro + WOF32_OFF / 4 + qu * 81;
    const float* xb = x + ((size_t)b * C1 + cg * 32) * HWN;

    float acc[9];
#pragma unroll
    for (int i = 0; i < 9; ++i) acc[i] = (cg == 0) ? b_off[qu * 9 + i] : 0.f;

    int hc0 = (h >= 1) ? h - 1 : 0, hc2 = (h < 127) ? h + 1 : 127;
    int wc0 = (w >= 1) ? w - 1 : 0, wc2 = (w < 127) ? w + 1 : 127;
    bool vh0 = (h >= 1), vh2 = (h < 127);
    bool vw0 = (w >= 1), vw2 = (w < 127);
    int o[9];
    o[0] = hc0 * 128 + wc0; o[1] = hc0 * 128 + w; o[2] = hc0 * 128 + wc2;
    o[3] = h   * 128 + wc0; o[4] = h   * 128 + w; o[5] = h   * 128 + wc2;
    o[6] = hc2 * 128 + wc0; o[7] = hc2 * 128 + w; o[8] = hc2 * 128 + wc2;
    bool vm[9];
    vm[0] = vh0 && vw0; vm[1] = vh0; vm[2] = vh0 && vw2;
    vm[3] = vw0;        vm[4] = true; vm[5] = vw2;
    vm[6] = vh2 && vw0; vm[7] = vh2; vm[8] = vh2 && vw2;

    for (int ci = 0; ci < 32; ++ci) {
      const float* xc = xb + (size_t)ci * HWN;
      float xv[9];
#pragma unroll
      for (int k = 0; k < 9; ++k) {
        float rr = xc[o[k]];
        xv[k] = vm[k] ? rr : 0.f;
      }
      const float* wp = wq + (cg * 32 + ci) * 162;   // wave-uniform -> scalar loads
#pragma unroll
      for (int tap = 0; tap < 9; ++tap)
#pragma unroll
        for (int i = 0; i < 9; ++i)
          acc[i] = fmaf(xv[tap], wp[tap * 9 + i], acc[i]);
    }
    int pos = (b * HH + h) * WW + w;
#pragma unroll
    for (int i = 0; i < 9; ++i)
      part[(size_t)(cg * 18 + qu * 9 + i) * 65536 + pos] = acc[i];
  } else {
    // ---- transpose_x body (verbatim R14) ----
    int bid = blk - 4 * BB * HH;
    int wt = bid & 1, h = (bid >> 1) & 127, cb = (bid >> 8) & 3, b = bid >> 10;
    int c0 = cb * 32, w0 = wt * 64;
    int wl = tid & 63, rr = tid >> 6;
#pragma unroll
    for (int it = 0; it < 8; ++it) {
      int ci = it * 4 + rr;
      tile[ci][wl] = f2bf(x[(((size_t)b * C1 + c0 + ci) * HWN) + h * WW + w0 + wl]);
    }
    __syncthreads();
    int wl2 = tid >> 2, cg = tid & 3;
    short8 pk;
#pragma unroll
    for (int k = 0; k < 8; ++k) pk[k] = (short)tile[cg * 8 + k][wl2];
    *(short8*)(ws_u + XT_OFF / 2 +
               (((size_t)(b * HH + h) * WW + w0 + wl2) * C1 + c0 + cg * 8)) = pk;
  }
}

// ---- reduce 4 SoA partial planes -> offp[oc][pos] (fallback mode only) ----
__global__ __launch_bounds__(256) void off_reduce_soa(
    const float* __restrict__ part, float* __restrict__ ws_f) {
  int e = blockIdx.x * 256 + threadIdx.x;   // over 18*65536
  int oc = e >> 16, pos = e & 65535;
  float s = part[(size_t)oc * 65536 + pos]
          + part[(size_t)(18 + oc) * 65536 + pos]
          + part[(size_t)(36 + oc) * 65536 + pos]
          + part[(size_t)(54 + oc) * 65536 + pos];
  ws_f[OFFP_OFF / 4 + (size_t)oc * 65536 + pos] = s;
}

// ------- fused gather + 16x16x32 MFMA GEMM + BN + SiLU (16 waves) -------
#define ALDS_STRIDE 136   // ushorts per 64-pos row (128 + 8 pad), 16B-aligned rows
__global__ __launch_bounds__(1024, 8) void akconv_main_mfma16(
    const ushort* ws_u, const float* ws_f, float* out, int fused) {
  __shared__ __align__(16) int4v sidx[576];          // 4 byte-offsets into xT b-plane
  __shared__ __align__(16) f32x4 swgt[576];          // 4 bilinear weights, f32
  __shared__ __align__(16) ushort alds[2][64 * ALDS_STRIDE];

  int tid = threadIdx.x;
  int blk = blockIdx.x;
  // XCD-aware decode: each XCD (blk&7) owns one b-plane and one 64-row h-band
  int xcd = blk & 7, idx = blk >> 3;
  int b  = xcd >> 1;
  int h  = ((xcd & 1) << 6) + (idx >> 1);
  int wt = idx & 1;
  int w0 = wt * 64;

  // phase A: bilinear offsets + weights; offsets either pre-reduced or 4-plane sum
  if (tid < 576) {
    int n = tid >> 6, wl = tid & 63;
    int pos = (b * HH + h) * WW + w0 + wl;
    float ox, oy;
    if (fused) {
      const float* pp = ws_f + PART_OFF / 4;
      ox = pp[(size_t)n * 65536 + pos]
         + pp[(size_t)(18 + n) * 65536 + pos]
         + pp[(size_t)(36 + n) * 65536 + pos]
         + pp[(size_t)(54 + n) * 65536 + pos];
      oy = pp[(size_t)(9 + n) * 65536 + pos]
         + pp[(size_t)(27 + n) * 65536 + pos]
         + pp[(size_t)(45 + n) * 65536 + pos]
         + pp[(size_t)(63 + n) * 65536 + pos];
    } else {
      const float* offp = ws_f + OFFP_OFF / 4;
      ox = offp[(size_t)n * 65536 + pos];
      oy = offp[(size_t)(9 + n) * 65536 + pos];
    }
    float px = ox + (float)(n / 3) + (float)h;
    float py = oy + (float)(n - (n / 3) * 3) + (float)(w0 + wl);
    px = fminf(fmaxf(px, 0.f), 127.f);
    py = fminf(fmaxf(py, 0.f), 127.f);
    float x0 = floorf(px), y0 = floorf(py);
    float x1 = fminf(x0 + 1.f, 127.f), y1 = fminf(y0 + 1.f, 127.f);
    f32x4 g;
    g[0] = (1.f + (x0 - px)) * (1.f + (y0 - py));
    g[1] = (1.f - (x1 - px)) * (1.f - (y1 - py));
    g[2] = (1.f + (x0 - px)) * (1.f - (y1 - py));
    g[3] = (1.f - (x1 - px)) * (1.f + (y0 - py));
    int ix0 = (int)x0, iy0 = (int)y0, ix1 = (int)x1, iy1 = (int)y1;
    int4v iv;
    iv[0] = (ix0 * WW + iy0) << 8;    // *256 B per (h,w) c-row
    iv[1] = (ix1 * WW + iy1) << 8;
    iv[2] = (ix0 * WW + iy1) << 8;
    iv[3] = (ix1 * WW + iy0) << 8;
    sidx[tid] = iv;
    swgt[tid] = g;
  }

  const char* xTb = (const char*)ws_u + (size_t)b * (HWN * 256);
  const ushort* wB3 = ws_u + WB3_OFF / 2;
  int lane = tid & 63, r = lane & 15, kg = lane >> 4;
  int wv = __builtin_amdgcn_readfirstlane(tid >> 6);   // wave = o-block 0..15

  // per-thread build slot: ONE (pos, 16B c-octet)
  int p   = tid >> 4;                 // 0..63
  int oct = tid & 15;
  int coff = oct * 16;
  int wr = p * ALDS_STRIDE + oct * 8;

  f32x4 acc[4];
#pragma unroll
  for (int mi = 0; mi < 4; ++mi) acc[mi] = (f32x4)0.0f;

  __syncthreads();   // sidx/swgt visible

  uint4v gv[4];
  f32x4 gw;

#define GLOAD(nn)                                                       \
  {                                                                     \
    int e = (nn) * 64 + p;                                              \
    int4v iv = sidx[e];                                                 \
    gw = swgt[e];                                                       \
    gv[0] = *(const uint4v*)(xTb + iv[0] + coff);                       \
    gv[1] = *(const uint4v*)(xTb + iv[1] + coff);                       \
    gv[2] = *(const uint4v*)(xTb + iv[2] + coff);                       \
    gv[3] = *(const uint4v*)(xTb + iv[3] + coff);                       \
  }

#define GCOMBINE(bufb)                                                  \
  {                                                                     \
    uint4v pkv;                                                         \
    _Pragma("unroll")                                                   \
    for (int jj = 0; jj < 4; ++jj) {                                    \
      float flo = gw[0] * u2f(gv[0][jj] << 16) + gw[1] * u2f(gv[1][jj] << 16) \
                + gw[2] * u2f(gv[2][jj] << 16) + gw[3] * u2f(gv[3][jj] << 16);\
      float fhi = gw[0] * u2f(gv[0][jj] & 0xffff0000u)                  \
                + gw[1] * u2f(gv[1][jj] & 0xffff0000u)                  \
                + gw[2] * u2f(gv[2][jj] & 0xffff0000u)                  \
                + gw[3] * u2f(gv[3][jj] & 0xffff0000u);                 \
      uint upk;                                                         \
      asm("v_cvt_pk_bf16_f32 %0, %1, %2" : "=v"(upk) : "v"(flo), "v"(fhi)); \
      pkv[jj] = upk;                                                    \
    }                                                                   \
    *(uint4v*)(&alds[bufb][wr]) = pkv;                                  \
  }

  // prologue: build n=0 into buf 0
  GLOAD(0);
  GCOMBINE(0);
  __syncthreads();

  for (int n = 0; n < 9; ++n) {
    int buf = n & 1;
    if (n < 8) GLOAD(n + 1);          // latency hides under MFMA via TLP
#pragma unroll
    for (int kc = 0; kc < 4; ++kc) {
      short8 bfrag = *(const short8*)(wB3 +
          (((size_t)(n * 16 + wv) * 4 + kc) * 64 + lane) * 8);   // contiguous 1KB/wave
#pragma unroll
      for (int mi = 0; mi < 4; ++mi) {
        short8 a = *(const short8*)(&alds[buf][(mi * 16 + r) * ALDS_STRIDE + (kc * 4 + kg) * 8]);
        acc[mi] = __builtin_amdgcn_mfma_f32_16x16x32_bf16(bfrag, a, acc[mi], 0, 0, 0);
      }
    }
    if (n < 8) GCOMBINE(buf ^ 1);
    __syncthreads();
  }
#undef GLOAD
#undef GCOMBINE

  // epilogue: BN + SiLU; D[row=o_sub][col=pos], stores coalesced along w
  const float* bnA = ws_f + BN_OFF / 4;
  const float* bnB = bnA + 256;
  int ob = wv * 16 + kg * 4;
#pragma unroll
  for (int j = 0; j < 4; ++j) {
    int o = ob + j;
    float sA = bnA[o], sB = bnB[o];
#pragma unroll
    for (int mi = 0; mi < 4; ++mi) {
      float v = acc[mi][j] * sA + sB;
      float sv = v / (1.f + __expf(-v));
      out[(((size_t)b * C2 + o) * HWN) + h * WW + w0 + mi * 16 + r] = sv;
    }
  }
}

extern "C" void kernel_launch(void* const* d_in, const int* in_sizes, int n_in,
                              void* d_out, int out_size, void* d_ws, size_t ws_size,
                              hipStream_t stream) {
  const float* x        = (const float*)d_in[0];
  const float* w_off    = (const float*)d_in[1];
  const float* b_off    = (const float*)d_in[2];
  const float* w_main   = (const float*)d_in[3];
  const float* bn_gamma = (const float*)d_in[4];
  const float* bn_beta  = (const float*)d_in[5];
  const float* bn_mean  = (const float*)d_in[6];
  const float* bn_var   = (const float*)d_in[7];
  ushort* ws_u = (ushort*)d_ws;
  float*  ws_f = (float*)d_ws;
  float*  out  = (float*)d_out;

  int fused = (ws_size >= WS_FUSED_NEED) ? 1 : 0;
  float* part_dst = fused ? (ws_f + PART_OFF / 4) : out;

  int prep_tasks = C1 * NPT * C2 + 128 * 2 * 81 + C2;   // 315904
  prep<<<(prep_tasks + 255) / 256, 256, 0, stream>>>(
      w_main, w_off, bn_gamma, bn_beta, bn_mean, bn_var, ws_u, ws_f);
  // stage1: off_conv (2048 blocks, long pole first) + transpose_x (4096 blocks), overlapped
  stage1<<<4 * BB * HH + BB * 4 * HH * 2, 256, 0, stream>>>(
      x, b_off, ws_f, ws_u, part_dst);
  if (!fused) {
    off_reduce_soa<<<(18 * 65536) / 256, 256, 0, stream>>>(out, ws_f);
  }
  akconv_main_mfma16<<<BB * HH * 2, 1024, 0, stream>>>(ws_u, ws_f, out, fused);
}

// Round 16
// 131.935 us; speedup vs baseline: 1.1949x; 1.0478x over previous
//
#include <hip/hip_runtime.h>
#include <math.h>

typedef __attribute__((ext_vector_type(8))) short short8;
typedef __attribute__((ext_vector_type(4))) float f32x4;
typedef __attribute__((ext_vector_type(2))) float f32x2;
typedef __attribute__((ext_vector_type(4))) uint  uint4v;
typedef __attribute__((ext_vector_type(4))) int   int4v;

#define BB  4
#define C1  128
#define C2  256
#define HH  128
#define WW  128
#define NPT 9
#define HWN (HH*WW)

// ---- workspace byte offsets ----
#define XT_OFF    0ull                        // bf16 xT[b][h][w][c]   : 16,777,216 B
#define WB3_OFF   16777216ull                 // bf16 wB3[n][ob][kc][lane][8] : 589,824 B
#define BN_OFF    (WB3_OFF + 589824ull)       // f32  bnA/bnB[256]     :      2,048 B
#define OFFP_OFF  (BN_OFF + 2048ull)          // f32  offp[18][65536] SoA : 4,718,592 B
#define PART_OFF  (OFFP_OFF + 4718592ull)     // f32  part[72][65536] (fused mode) : 18,874,368 B
#define WS_FUSED_NEED (PART_OFF + 18874368ull) // < 41 MB (proven available in R14)

// stage1 block ranges
#define NB_OFF  (4 * BB * HH)                 // 2048 off_conv blocks
#define NB_TR   (BB * 4 * HH * 2)             // 4096 transpose blocks
#define NB_PREP 1153                          // (294912 + 256) / 256

__device__ __forceinline__ ushort f2bf(float f) {
  uint u = __builtin_bit_cast(uint, f);
  u += 0x7FFFu + ((u >> 16) & 1u);            // RNE
  return (ushort)(u >> 16);
}
__device__ __forceinline__ float u2f(uint u) {
  return __builtin_bit_cast(float, u);
}

// ---------------- stage1: off_conv + transpose_x + weight/BN prep, one dispatch ----------------
__global__ __launch_bounds__(256) void stage1(
    const float* __restrict__ x, const float* __restrict__ b_off,
    const float* __restrict__ w_off, const float* __restrict__ w_main,
    const float* __restrict__ g, const float* __restrict__ be,
    const float* __restrict__ mu, const float* __restrict__ var,
    ushort* ws_u, float* ws_f, float* __restrict__ part) {
  __shared__ __align__(16) ushort tile[32][68];
  int blk = blockIdx.x;
  int tid = threadIdx.x;

  if (blk < NB_OFF) {
    // ---- fp32 offset conv, channel-split x4, direct w_off reads, packed-f32 FMA ----
    int cg = blk & 3, bh = blk >> 2;          // cg: 32-channel group
    int h = bh & 127, b = bh >> 7;
    int w = tid & 127, q = tid >> 7;
    int qu = __builtin_amdgcn_readfirstlane(q);
    int quoff = qu * 9;
    const float* xb = x + ((size_t)b * C1 + cg * 32) * HWN;

    f32x2 acc2[9];
    float accs[9];
#pragma unroll
    for (int i = 0; i < 9; ++i) {
      acc2[i] = (f32x2)0.0f;
      accs[i] = (cg == 0) ? b_off[quoff + i] : 0.f;
    }

    int hc0 = (h >= 1) ? h - 1 : 0, hc2 = (h < 127) ? h + 1 : 127;
    int wc0 = (w >= 1) ? w - 1 : 0, wc2 = (w < 127) ? w + 1 : 127;
    bool vh0 = (h >= 1), vh2 = (h < 127);
    bool vw0 = (w >= 1), vw2 = (w < 127);
    int o[9];
    o[0] = hc0 * 128 + wc0; o[1] = hc0 * 128 + w; o[2] = hc0 * 128 + wc2;
    o[3] = h   * 128 + wc0; o[4] = h   * 128 + w; o[5] = h   * 128 + wc2;
    o[6] = hc2 * 128 + wc0; o[7] = hc2 * 128 + w; o[8] = hc2 * 128 + wc2;
    bool vm[9];
    vm[0] = vh0 && vw0; vm[1] = vh0; vm[2] = vh0 && vw2;
    vm[3] = vw0;        vm[4] = true; vm[5] = vw2;
    vm[6] = vh2 && vw0; vm[7] = vh2; vm[8] = vh2 && vw2;

    for (int ci = 0; ci < 32; ++ci) {
      int c = cg * 32 + ci;
      const float* xc = xb + (size_t)ci * HWN;
      float xv[9];
#pragma unroll
      for (int k = 0; k < 9; ++k) {
        float rr = xc[o[k]];
        xv[k] = vm[k] ? rr : 0.f;
      }
      f32x2 xp0 = {xv[0], xv[1]}, xp1 = {xv[2], xv[3]};
      f32x2 xp2 = {xv[4], xv[5]}, xp3 = {xv[6], xv[7]};
      float x8 = xv[8];
#pragma unroll
      for (int i = 0; i < 9; ++i) {
        // taps contiguous in original w_off layout; wave-uniform -> s_loads
        const float* wp = w_off + ((size_t)(quoff + i) * C1 + c) * 9;
        f32x2 w01 = {wp[0], wp[1]}, w23 = {wp[2], wp[3]};
        f32x2 w45 = {wp[4], wp[5]}, w67 = {wp[6], wp[7]};
        acc2[i] = xp0 * w01 + acc2[i];     // -ffp-contract -> v_pk_fma_f32
        acc2[i] = xp1 * w23 + acc2[i];
        acc2[i] = xp2 * w45 + acc2[i];
        acc2[i] = xp3 * w67 + acc2[i];
        accs[i] = fmaf(x8, wp[8], accs[i]);
      }
    }
    int pos = (b * HH + h) * WW + w;
#pragma unroll
    for (int i = 0; i < 9; ++i)
      part[(size_t)(cg * 18 + quoff + i) * 65536 + pos] = acc2[i][0] + acc2[i][1] + accs[i];

  } else if (blk < NB_OFF + NB_TR) {
    // ---- transpose_x body (verbatim) ----
    int bid = blk - NB_OFF;
    int wt = bid & 1, h = (bid >> 1) & 127, cb = (bid >> 8) & 3, b = bid >> 10;
    int c0 = cb * 32, w0 = wt * 64;
    int wl = tid & 63, rr = tid >> 6;
#pragma unroll
    for (int it = 0; it < 8; ++it) {
      int ci = it * 4 + rr;
      tile[ci][wl] = f2bf(x[(((size_t)b * C1 + c0 + ci) * HWN) + h * WW + w0 + wl]);
    }
    __syncthreads();
    int wl2 = tid >> 2, cg = tid & 3;
    short8 pk;
#pragma unroll
    for (int k = 0; k < 8; ++k) pk[k] = (short)tile[cg * 8 + k][wl2];
    *(short8*)(ws_u + XT_OFF / 2 +
               (((size_t)(b * HH + h) * WW + w0 + wl2) * C1 + c0 + cg * 8)) = pk;

  } else {
    // ---- weight/BN prep (consumed only by the main kernel, after stage1) ----
    int t = (blk - NB_OFF - NB_TR) * 256 + tid;
    if (t < C1 * NPT * C2) {
      // wB3: j=t&7, lane=(t>>3)&63, kc=(t>>9)&3, ob=(t>>11)&15, n=t>>15
      int j = t & 7, lane = (t >> 3) & 63, kc = (t >> 9) & 3;
      int ob = (t >> 11) & 15, n = t >> 15;
      int o = ob * 16 + (lane & 15);
      int c = kc * 32 + (lane >> 4) * 8 + j;
      ws_u[WB3_OFF / 2 + t] = f2bf(w_main[(o * C1 + c) * NPT + n]);
    } else {
      int o = t - C1 * NPT * C2;        // 0..255
      float inv = g[o] * rsqrtf(var[o] + 1e-5f);
      ws_f[BN_OFF / 4 + o] = inv;
      ws_f[BN_OFF / 4 + 256 + o] = be[o] - mu[o] * inv;
    }
  }
}

// ---- reduce 4 SoA partial planes -> offp[oc][pos] (fallback mode only) ----
__global__ __launch_bounds__(256) void off_reduce_soa(
    const float* __restrict__ part, float* __restrict__ ws_f) {
  int e = blockIdx.x * 256 + threadIdx.x;   // over 18*65536
  int oc = e >> 16, pos = e & 65535;
  float s = part[(size_t)oc * 65536 + pos]
          + part[(size_t)(18 + oc) * 65536 + pos]
          + part[(size_t)(36 + oc) * 65536 + pos]
          + part[(size_t)(54 + oc) * 65536 + pos];
  ws_f[OFFP_OFF / 4 + (size_t)oc * 65536 + pos] = s;
}

// ------- fused gather + 16x16x32 MFMA GEMM + BN + SiLU (16 waves) -------
#define ALDS_STRIDE 136   // ushorts per 64-pos row (128 + 8 pad), 16B-aligned rows
__global__ __launch_bounds__(1024, 8) void akconv_main_mfma16(
    const ushort* ws_u, const float* ws_f, float* out, int fused) {
  __shared__ __align__(16) int4v sidx[576];          // 4 byte-offsets into xT b-plane
  __shared__ __align__(16) f32x4 swgt[576];          // 4 bilinear weights, f32
  __shared__ __align__(16) ushort alds[2][64 * ALDS_STRIDE];

  int tid = threadIdx.x;
  int blk = blockIdx.x;
  // XCD-aware decode: each XCD (blk&7) owns one b-plane and one 64-row h-band
  int xcd = blk & 7, idx = blk >> 3;
  int b  = xcd >> 1;
  int h  = ((xcd & 1) << 6) + (idx >> 1);
  int wt = idx & 1;
  int w0 = wt * 64;

  // phase A: bilinear offsets + weights; offsets either pre-reduced or 4-plane sum
  if (tid < 576) {
    int n = tid >> 6, wl = tid & 63;
    int pos = (b * HH + h) * WW + w0 + wl;
    float ox, oy;
    if (fused) {
      const float* pp = ws_f + PART_OFF / 4;
      ox = pp[(size_t)n * 65536 + pos]
         + pp[(size_t)(18 + n) * 65536 + pos]
         + pp[(size_t)(36 + n) * 65536 + pos]
         + pp[(size_t)(54 + n) * 65536 + pos];
      oy = pp[(size_t)(9 + n) * 65536 + pos]
         + pp[(size_t)(27 + n) * 65536 + pos]
         + pp[(size_t)(45 + n) * 65536 + pos]
         + pp[(size_t)(63 + n) * 65536 + pos];
    } else {
      const float* offp = ws_f + OFFP_OFF / 4;
      ox = offp[(size_t)n * 65536 + pos];
      oy = offp[(size_t)(9 + n) * 65536 + pos];
    }
    float px = ox + (float)(n / 3) + (float)h;
    float py = oy + (float)(n - (n / 3) * 3) + (float)(w0 + wl);
    px = fminf(fmaxf(px, 0.f), 127.f);
    py = fminf(fmaxf(py, 0.f), 127.f);
    float x0 = floorf(px), y0 = floorf(py);
    float x1 = fminf(x0 + 1.f, 127.f), y1 = fminf(y0 + 1.f, 127.f);
    f32x4 g;
    g[0] = (1.f + (x0 - px)) * (1.f + (y0 - py));
    g[1] = (1.f - (x1 - px)) * (1.f - (y1 - py));
    g[2] = (1.f + (x0 - px)) * (1.f - (y1 - py));
    g[3] = (1.f - (x1 - px)) * (1.f + (y0 - py));
    int ix0 = (int)x0, iy0 = (int)y0, ix1 = (int)x1, iy1 = (int)y1;
    int4v iv;
    iv[0] = (ix0 * WW + iy0) << 8;    // *256 B per (h,w) c-row
    iv[1] = (ix1 * WW + iy1) << 8;
    iv[2] = (ix0 * WW + iy1) << 8;
    iv[3] = (ix1 * WW + iy0) << 8;
    sidx[tid] = iv;
    swgt[tid] = g;
  }

  const char* xTb = (const char*)ws_u + (size_t)b * (HWN * 256);
  const ushort* wB3 = ws_u + WB3_OFF / 2;
  int lane = tid & 63, r = lane & 15, kg = lane >> 4;
  int wv = __builtin_amdgcn_readfirstlane(tid >> 6);   // wave = o-block 0..15

  // per-thread build slot: ONE (pos, 16B c-octet)
  int p   = tid >> 4;                 // 0..63
  int oct = tid & 15;
  int coff = oct * 16;
  int wr = p * ALDS_STRIDE + oct * 8;

  f32x4 acc[4];
#pragma unroll
  for (int mi = 0; mi < 4; ++mi) acc[mi] = (f32x4)0.0f;

  __syncthreads();   // sidx/swgt visible

  uint4v gv[4];
  f32x4 gw;

#define GLOAD(nn)                                                       \
  {                                                                     \
    int e = (nn) * 64 + p;                                              \
    int4v iv = sidx[e];                                                 \
    gw = swgt[e];                                                       \
    gv[0] = *(const uint4v*)(xTb + iv[0] + coff);                       \
    gv[1] = *(const uint4v*)(xTb + iv[1] + coff);                       \
    gv[2] = *(const uint4v*)(xTb + iv[2] + coff);                       \
    gv[3] = *(const uint4v*)(xTb + iv[3] + coff);                       \
  }

#define GCOMBINE(bufb)                                                  \
  {                                                                     \
    uint4v pkv;                                                         \
    _Pragma("unroll")                                                   \
    for (int jj = 0; jj < 4; ++jj) {                                    \
      float flo = gw[0] * u2f(gv[0][jj] << 16) + gw[1] * u2f(gv[1][jj] << 16) \
                + gw[2] * u2f(gv[2][jj] << 16) + gw[3] * u2f(gv[3][jj] << 16);\
      float fhi = gw[0] * u2f(gv[0][jj] & 0xffff0000u)                  \
                + gw[1] * u2f(gv[1][jj] & 0xffff0000u)                  \
                + gw[2] * u2f(gv[2][jj] & 0xffff0000u)                  \
                + gw[3] * u2f(gv[3][jj] & 0xffff0000u);                 \
      uint upk;                                                         \
      asm("v_cvt_pk_bf16_f32 %0, %1, %2" : "=v"(upk) : "v"(flo), "v"(fhi)); \
      pkv[jj] = upk;                                                    \
    }                                                                   \
    *(uint4v*)(&alds[bufb][wr]) = pkv;                                  \
  }

  // prologue: build n=0 into buf 0
  GLOAD(0);
  GCOMBINE(0);
  __syncthreads();

  for (int n = 0; n < 9; ++n) {
    int buf = n & 1;
    if (n < 8) GLOAD(n + 1);          // latency hides under MFMA via TLP
#pragma unroll
    for (int kc = 0; kc < 4; ++kc) {
      short8 bfrag = *(const short8*)(wB3 +
          (((size_t)(n * 16 + wv) * 4 + kc) * 64 + lane) * 8);   // contiguous 1KB/wave
#pragma unroll
      for (int mi = 0; mi < 4; ++mi) {
        short8 a = *(const short8*)(&alds[buf][(mi * 16 + r) * ALDS_STRIDE + (kc * 4 + kg) * 8]);
        acc[mi] = __builtin_amdgcn_mfma_f32_16x16x32_bf16(bfrag, a, acc[mi], 0, 0, 0);
      }
    }
    if (n < 8) GCOMBINE(buf ^ 1);
    __syncthreads();
  }
#undef GLOAD
#undef GCOMBINE

  // epilogue: BN + SiLU; D[row=o_sub][col=pos], stores coalesced along w
  const float* bnA = ws_f + BN_OFF / 4;
  const float* bnB = bnA + 256;
  int ob = wv * 16 + kg * 4;
#pragma unroll
  for (int j = 0; j < 4; ++j) {
    int o = ob + j;
    float sA = bnA[o], sB = bnB[o];
#pragma unroll
    for (int mi = 0; mi < 4; ++mi) {
      float v = acc[mi][j] * sA + sB;
      float sv = v / (1.f + __expf(-v));
      out[(((size_t)b * C2 + o) * HWN) + h * WW + w0 + mi * 16 + r] = sv;
    }
  }
}

extern "C" void kernel_launch(void* const* d_in, const int* in_sizes, int n_in,
                              void* d_out, int out_size, void* d_ws, size_t ws_size,
                              hipStream_t stream) {
  const float* x        = (const float*)d_in[0];
  const float* w_off    = (const float*)d_in[1];
  const float* b_off    = (const float*)d_in[2];
  const float* w_main   = (const float*)d_in[3];
  const float* bn_gamma = (const float*)d_in[4];
  const float* bn_beta  = (const float*)d_in[5];
  const float* bn_mean  = (const float*)d_in[6];
  const float* bn_var   = (const float*)d_in[7];
  ushort* ws_u = (ushort*)d_ws;
  float*  ws_f = (float*)d_ws;
  float*  out  = (float*)d_out;

  int fused = (ws_size >= WS_FUSED_NEED) ? 1 : 0;
  float* part_dst = fused ? (ws_f + PART_OFF / 4) : out;

  // stage1: off_conv (long pole first) + transpose_x + prep, one dispatch
  stage1<<<NB_OFF + NB_TR + NB_PREP, 256, 0, stream>>>(
      x, b_off, w_off, w_main, bn_gamma, bn_beta, bn_mean, bn_var,
      ws_u, ws_f, part_dst);
  if (!fused) {
    off_reduce_soa<<<(18 * 65536) / 256, 256, 0, stream>>>(out, ws_f);
  }
  akconv_main_mfma16<<<BB * HH * 2, 1024, 0, stream>>>(ws_u, ws_f, out, fused);
}